// Round 15
// baseline (691.485 us; speedup 1.0000x reference)
//
#include <hip/hip_runtime.h>
#include <hip/hip_bf16.h>

#define TOTALROWS 262144
#define NSEG      1024
#define SEGROWS   256
#define HD        64
#define DEMB      32
#define DPRE      96
#define N1        512
#define N2        1024
#define EPSB      1e-5f

typedef short s16x8 __attribute__((ext_vector_type(8)));
typedef short s16x4 __attribute__((ext_vector_type(4)));
typedef float f32x4 __attribute__((ext_vector_type(4)));

static __device__ __forceinline__ ushort f2bf(float x) {
    union { float f; unsigned u; } v; v.f = x;
    unsigned r = v.u + 0x7FFFu + ((v.u >> 16) & 1u);   // round-to-nearest-even
    return (ushort)(r >> 16);
}

// async global->LDS, 16B per lane; LDS dest = wave-uniform base + lane*16
static __device__ __forceinline__ void gload_lds16(const void* g, void* l) {
    __builtin_amdgcn_global_load_lds(
        (const __attribute__((address_space(1))) void*)g,
        (__attribute__((address_space(3))) void*)l, 16, 0, 0);
}

// ---------------- W2 + W1 f32 -> bf16 (canonical row-major) ----------------
__global__ void convert_w_kernel(const float* __restrict__ w2, ushort* __restrict__ w2b,
                                 const float* __restrict__ w1, ushort* __restrict__ w1b) {
    int i = blockIdx.x * 256 + threadIdx.x;
    const float* src; ushort* dst; int j;
    if (i < 131072) { src = w2; dst = w2b; j = i; }
    else            { src = w1; dst = w1b; j = i - 131072; if (j >= 12288) return; }
    float4 v = ((const float4*)src)[j];
    ushort4 o;
    o.x = f2bf(v.x); o.y = f2bf(v.y); o.z = f2bf(v.z); o.w = f2bf(v.w);
    ((ushort4*)dst)[j] = o;
}

// ---------------- layer 1: single-pass per segment (EXACT round-13 best) ----------------
__global__ __launch_bounds__(512, 2) void layer1_kernel(
    const float* __restrict__ hstate, const float* __restrict__ ebpr,
    const float* __restrict__ Wsp, const ushort* __restrict__ W1b,
    const float* __restrict__ g1, const float* __restrict__ be1,
    ushort* __restrict__ h1)
{
    __shared__ __align__(16) ushort As[SEGROWS * 104];   // mlp_in [256][96] pad->104
    __shared__ __align__(16) ushort Bs[SEGROWS * 104];   // W1 half [256][96] pad->104
    __shared__ float statsS[8][4][16];
    __shared__ float statsQ[8][4][16];

    const int seg  = blockIdx.x;
    const int tid  = threadIdx.x;
    const int lane = tid & 63, wid = tid >> 6;
    const int wr   = wid >> 2, wc = wid & 3;

    // --- A cols 32..95 = h_state: one ds_write_b128 per 8 floats ---
    {
        const float4* hs4 = (const float4*)(hstate + (size_t)seg * SEGROWS * HD);
        #pragma unroll
        for (int i = 0; i < 4; ++i) {
            int u = tid + i * 512;                 // 2048 8-float chunks
            int r = u >> 3, c8 = u & 7;
            float4 v0 = hs4[2 * u];
            float4 v1 = hs4[2 * u + 1];
            s16x8 o;
            o[0] = (short)f2bf(v0.x); o[1] = (short)f2bf(v0.y);
            o[2] = (short)f2bf(v0.z); o[3] = (short)f2bf(v0.w);
            o[4] = (short)f2bf(v1.x); o[5] = (short)f2bf(v1.y);
            o[6] = (short)f2bf(v1.z); o[7] = (short)f2bf(v1.w);
            *(s16x8*)&As[r * 104 + DEMB + c8 * 8] = o;
        }
    }
    // --- A cols 0..31 = rel_emb: one ds_write_b64 per 4 outputs ---
    {
        #pragma unroll
        for (int i = 0; i < 4; ++i) {
            int u = tid + i * 512;                 // 2048 k-quads
            int r = u >> 3, kq = u & 7;
            float4 e = ((const float4*)ebpr)[seg * SEGROWS + r];
            s16x4 o;
            #pragma unroll
            for (int t = 0; t < 4; ++t) {
                float4 w = ((const float4*)Wsp)[kq * 4 + t];
                // pos = [e0, e2, e1, e3] (transpose (0,2,1) of (2,BF))
                float val = w.x * e.x + w.y * e.z + w.z * e.y + w.w * e.w;
                o[t] = (short)f2bf(val);           // b_sp cancels through segment BN
            }
            *(s16x4*)&As[r * 104 + kq * 4] = o;
        }
    }

    #pragma unroll 1
    for (int ct = 0; ct < 2; ++ct) {
        // --- B tile: pre-converted W1b rows ct*256..+256 ---
        {
            const s16x8* w18 = (const s16x8*)(W1b + (size_t)ct * 256 * DPRE);
            #pragma unroll
            for (int i = 0; i < 6; ++i) {
                int u = tid + i * 512;             // 3072 16B chunks
                int r = u / 12, c8 = u % 12;
                *(s16x8*)&Bs[r * 104 + c8 * 8] = w18[u];
            }
        }
        __syncthreads();                           // As and Bs ready

        f32x4 acc[8][4] = {};
        const int arow0 = wr * 128 + (lane & 15);
        const int bcol0 = wc * 64  + (lane & 15);
        const int kg    = (lane >> 4) * 8;
        #pragma unroll
        for (int ks = 0; ks < 3; ++ks) {
            s16x8 af[8], bfr[4];
            #pragma unroll
            for (int m = 0; m < 8; ++m)
                af[m] = *(const s16x8*)&As[(arow0 + m * 16) * 104 + ks * 32 + kg];
            #pragma unroll
            for (int n = 0; n < 4; ++n)
                bfr[n] = *(const s16x8*)&Bs[(bcol0 + n * 16) * 104 + ks * 32 + kg];
            #pragma unroll
            for (int m = 0; m < 8; ++m)
                #pragma unroll
                for (int n = 0; n < 4; ++n)
                    acc[m][n] = __builtin_amdgcn_mfma_f32_16x16x32_bf16(af[m], bfr[n], acc[m][n], 0, 0, 0);
        }

        // --- per-column stats over the 256 segment rows ---
        float s[4], q[4];
        #pragma unroll
        for (int n = 0; n < 4; ++n) { s[n] = 0.f; q[n] = 0.f; }
        #pragma unroll
        for (int m = 0; m < 8; ++m)
            #pragma unroll
            for (int n = 0; n < 4; ++n)
                #pragma unroll
                for (int j = 0; j < 4; ++j) { float v = acc[m][n][j]; s[n] += v; q[n] += v * v; }
        #pragma unroll
        for (int n = 0; n < 4; ++n) {
            s[n] += __shfl_xor(s[n], 16); q[n] += __shfl_xor(q[n], 16);
            s[n] += __shfl_xor(s[n], 32); q[n] += __shfl_xor(q[n], 32);
        }
        if ((lane >> 4) == 0) {
            #pragma unroll
            for (int n = 0; n < 4; ++n) { statsS[wid][n][lane] = s[n]; statsQ[wid][n][lane] = q[n]; }
        }
        __syncthreads();

        const float inv256 = 1.0f / 256.0f;
        float aa[4], bb[4];
        const int c16 = lane & 15;
        #pragma unroll
        for (int n = 0; n < 4; ++n) {
            float sum = statsS[wc][n][c16] + statsS[4 + wc][n][c16];
            float sq  = statsQ[wc][n][c16] + statsQ[4 + wc][n][c16];
            float mean = sum * inv256;
            float var  = sq * inv256 - mean * mean;
            float rinv = rsqrtf(var + EPSB);
            int col = ct * 256 + wc * 64 + n * 16 + c16;
            aa[n] = g1[col] * rinv;
            bb[n] = be1[col] - mean * aa[n];
        }

        ushort* outp = h1 + (size_t)(seg * SEGROWS) * N1 + ct * 256;
        const int rbase = wr * 128 + (lane >> 4) * 4;
        #pragma unroll
        for (int m = 0; m < 8; ++m)
            #pragma unroll
            for (int j = 0; j < 4; ++j) {
                int r = rbase + m * 16 + j;
                ushort* rowp = outp + (size_t)r * N1 + wc * 64 + c16;
                #pragma unroll
                for (int n = 0; n < 4; ++n) {
                    float v = acc[m][n][j] * aa[n] + bb[n];
                    v = v > 0.f ? v : 0.f;
                    rowp[n * 16] = f2bf(v);
                }
            }
        __syncthreads();   // Bs/stats dead before next ct
    }
}

// ==================== layer 2: 256x128, 8 waves of 64x64, 3-deep lead-2, 2 blocks/CU ====================
// R14 budget analysis: per block, out-writes = 262KB = ~26k cycles of HBM
// drain, all serial in the epilogue at 1 block/CU; plus per-K-step vmcnt
// stalls. Fix needs 2 blocks/CU (sibling's K-loop absorbs the write burst),
// which the acc-register triangle allows ONLY at wave tile 64x64 (acc = 64
// VGPR -> total ~110 < 128 cap of launch_bounds(512,4)).
// Ancestors' failure causes, each now removed: R4 = 4 waves + nt-stores;
// R8 = launch_bounds(1024,8) spill; R9 = lead-1 (full HBM stall every step).
// This = R9's PASSING kernel with only {2->3 buffers, lead-1->lead-2, vmcnt}.
//
// LDS: A 3x16KB + B 3x8KB + stats 4KB = 76KB -> 2 blocks/CU. Grid 8192,
// bijective XCD swizzle: 8 ct-siblings of a segment share the A panel in L2.
//
// Sync invariant: step t: stage(t+2) [3 loads -> 9 in flight] ; vmcnt(6)
// retires ALL of tile t (t+1,t+2 remain) ; barrier (block-wide guarantee) ;
// compute(t) ; sched_barrier+barrier (WAR seal: buf[(t+2)%3]'s readers done
// before the NEXT step's stage). Tail: t=14 no stage -> vmcnt(3); t=15 -> 0.
// Prologue: stage 0,1 (6 loads); step 0 stages tile 2 then vmcnt(6).

static __device__ __forceinline__ void stage_tile(
    const char* gA, const char* gB, char* lA, char* lB,
    int t, int wid, int lane)
{
    const int rsub = lane >> 2;                               // 16 rows per group
    const int cl   = (((lane & 3) ^ ((lane >> 3) & 3)) << 4); // inverse-swz chunk
    #pragma unroll
    for (int i = 0; i < 2; ++i) {
        int g = i * 8 + wid;                                  // 0..15 -> 256 A rows
        gload_lds16(gA + (size_t)(g * 16 + rsub) * 1024 + (size_t)t * 64 + cl,
                    lA + g * 1024);
    }
    // B: 128 rows, group = wid (0..7)
    gload_lds16(gB + (size_t)(wid * 16 + rsub) * 1024 + (size_t)t * 64 + cl,
                lB + wid * 1024);
}

static __device__ __forceinline__ void compute_step(
    const ushort* lA, const ushort* lB, f32x4 (&acc)[4][4],
    int arow0, int bcol0, int swz)
{
    s16x8 af[4], bfr[4];
    #pragma unroll
    for (int m = 0; m < 4; ++m)
        af[m] = *(const s16x8*)&lA[(arow0 + m * 16) * 32 + swz];
    #pragma unroll
    for (int n = 0; n < 4; ++n)
        bfr[n] = *(const s16x8*)&lB[(bcol0 + n * 16) * 32 + swz];
    __builtin_amdgcn_s_setprio(1);
    #pragma unroll
    for (int m = 0; m < 4; ++m)
        #pragma unroll
        for (int n = 0; n < 4; ++n)
            acc[m][n] = __builtin_amdgcn_mfma_f32_16x16x32_bf16(af[m], bfr[n], acc[m][n], 0, 0, 0);
    __builtin_amdgcn_s_setprio(0);
}

__global__ __launch_bounds__(512, 4) void layer2_kernel(
    const ushort* __restrict__ h1, const ushort* __restrict__ W2b,
    const float* __restrict__ g2, const float* __restrict__ be2,
    float* __restrict__ out)
{
    __shared__ __align__(16) ushort As[3][SEGROWS * 32];  // 3 x 16 KiB
    __shared__ __align__(16) ushort Bs[3][128 * 32];      // 3 x 8 KiB
    __shared__ float statsS[8][4][16];
    __shared__ float statsQ[8][4][16];

    // bijective XCD swizzle (nwg=8192 % 8 == 0): the 8 ct-siblings of a segment
    // run on one XCD -> h1 A-panel (256KB) L2-hits most of 8 times.
    const int b   = blockIdx.x;
    const int wg  = (b & 7) * 1024 + (b >> 3);
    const int seg = wg >> 3;
    const int ct  = wg & 7;

    const int tid  = threadIdx.x;
    const int lane = tid & 63, wid = tid >> 6;    // wid 0..7
    const int wr   = wid >> 1, wc = wid & 1;      // 4M x 2N wave grid, 64x64 tiles

    const char* srcA = (const char*)(h1  + (size_t)seg * SEGROWS * N1);
    const char* srcB = (const char*)(W2b + (size_t)ct  * 128    * N1);

    f32x4 acc[4][4] = {};
    const int arow0 = wr * 64 + (lane & 15);      // 0..255
    const int bcol0 = wc * 64 + (lane & 15);      // 0..127
    const int swz   = (((lane >> 4) ^ ((lane >> 1) & 3)) << 3);

    // prologue: tiles 0,1 staged (6 loads/thread in flight)
    stage_tile(srcA, srcB, (char*)As[0], (char*)Bs[0], 0, wid, lane);
    stage_tile(srcA, srcB, (char*)As[1], (char*)Bs[1], 1, wid, lane);

#define L2_STEP(T, VW)                                                           \
    {                                                                            \
        if ((T) + 2 < 16)                                                        \
            stage_tile(srcA, srcB, (char*)As[((T)+2)%3], (char*)Bs[((T)+2)%3],   \
                       (T)+2, wid, lane);                                        \
        asm volatile("s_waitcnt vmcnt(" #VW ")" ::: "memory");                   \
        __builtin_amdgcn_s_barrier();                                            \
        compute_step(As[(T)%3], Bs[(T)%3], acc, arow0, bcol0, swz);              \
        __builtin_amdgcn_sched_barrier(0);                                       \
        asm volatile("s_barrier" ::: "memory");                                  \
    }

    L2_STEP(0, 6)   L2_STEP(1, 6)   L2_STEP(2, 6)   L2_STEP(3, 6)
    L2_STEP(4, 6)   L2_STEP(5, 6)   L2_STEP(6, 6)   L2_STEP(7, 6)
    L2_STEP(8, 6)   L2_STEP(9, 6)   L2_STEP(10, 6)  L2_STEP(11, 6)
    L2_STEP(12, 6)  L2_STEP(13, 6)  L2_STEP(14, 3)  L2_STEP(15, 0)
#undef L2_STEP

    // --- per-column stats: each wave covers 64 rows; combine the 4 wr-waves ---
    float s[4], q[4];
    #pragma unroll
    for (int n = 0; n < 4; ++n) { s[n] = 0.f; q[n] = 0.f; }
    #pragma unroll
    for (int m = 0; m < 4; ++m)
        #pragma unroll
        for (int n = 0; n < 4; ++n)
            #pragma unroll
            for (int j = 0; j < 4; ++j) { float v = acc[m][n][j]; s[n] += v; q[n] += v * v; }
    #pragma unroll
    for (int n = 0; n < 4; ++n) {
        s[n] += __shfl_xor(s[n], 16); q[n] += __shfl_xor(q[n], 16);
        s[n] += __shfl_xor(s[n], 32); q[n] += __shfl_xor(q[n], 32);
    }
    if ((lane >> 4) == 0) {
        #pragma unroll
        for (int n = 0; n < 4; ++n) { statsS[wid][n][lane] = s[n]; statsQ[wid][n][lane] = q[n]; }
    }
    __syncthreads();

    const float inv256 = 1.0f / 256.0f;
    float aa[4], bb[4];
    const int c16 = lane & 15;
    #pragma unroll
    for (int n = 0; n < 4; ++n) {
        // wid = wr*2 + wc: sum over wr = 0..3 for this wave's wc
        float sum = statsS[wc][n][c16] + statsS[2 + wc][n][c16]
                  + statsS[4 + wc][n][c16] + statsS[6 + wc][n][c16];
        float sq  = statsQ[wc][n][c16] + statsQ[2 + wc][n][c16]
                  + statsQ[4 + wc][n][c16] + statsQ[6 + wc][n][c16];
        float mean = sum * inv256;
        float var  = sq * inv256 - mean * mean;
        float rinv = rsqrtf(var + EPSB);
        int col = ct * 128 + wc * 64 + n * 16 + c16;
        aa[n] = g2[col] * rinv;
        bb[n] = be2[col] - mean * aa[n];
    }

    float* outp = out + (size_t)(seg * SEGROWS) * N2 + ct * 128;
    const int rbase = wr * 64 + (lane >> 4) * 4;
    #pragma unroll
    for (int m = 0; m < 4; ++m)
        #pragma unroll
        for (int j = 0; j < 4; ++j) {
            int r = rbase + m * 16 + j;
            float* rowp = outp + (size_t)r * N2 + wc * 64 + c16;
            #pragma unroll
            for (int n = 0; n < 4; ++n) {
                float v = acc[m][n][j] * aa[n] + bb[n];
                v = v > 0.f ? v : 0.f;
                rowp[n * 16] = v;
            }
        }
}

extern "C" void kernel_launch(void* const* d_in, const int* in_sizes, int n_in,
                              void* d_out, int out_size, void* d_ws, size_t ws_size,
                              hipStream_t stream) {
    const float* hstate = (const float*)d_in[0];
    const float* ebpr   = (const float*)d_in[1];
    const float* Wsp    = (const float*)d_in[2];
    // d_in[3] = b_sp  : cancels through segment BN (exact)
    const float* W1     = (const float*)d_in[4];
    // d_in[5] = b1    : cancels through segment BN (exact)
    const float* g1     = (const float*)d_in[6];
    const float* be1    = (const float*)d_in[7];
    const float* W2     = (const float*)d_in[8];
    // d_in[9] = b2    : cancels through segment BN (exact)
    const float* g2     = (const float*)d_in[10];
    const float* be2    = (const float*)d_in[11];
    float* outp         = (float*)d_out;

    ushort* h1  = (ushort*)d_ws;                          // 262144 x 512 bf16 = 256 MiB
    ushort* W2b = h1 + (size_t)TOTALROWS * N1;            // 1024 x 512 bf16 = 1 MiB
    ushort* W1b = W2b + (size_t)N2 * N1;                  // 512 x 96 bf16

    convert_w_kernel<<<dim3(560), dim3(256), 0, stream>>>(W2, W2b, W1, W1b);
    layer1_kernel<<<dim3(NSEG), dim3(512), 0, stream>>>(hstate, ebpr, Wsp, W1b, g1, be1, h1);
    layer2_kernel<<<dim3(8192), dim3(512), 0, stream>>>(h1, W2b, g2, be2, outp);
}

// Round 16
// 584.669 us; speedup vs baseline: 1.1827x; 1.1827x over previous
//
#include <hip/hip_runtime.h>
#include <hip/hip_bf16.h>

#define TOTALROWS 262144
#define NSEG      1024
#define SEGROWS   256
#define HD        64
#define DEMB      32
#define DPRE      96
#define N1        512
#define N2        1024
#define EPSB      1e-5f

typedef short s16x8 __attribute__((ext_vector_type(8)));
typedef short s16x4 __attribute__((ext_vector_type(4)));
typedef float f32x4 __attribute__((ext_vector_type(4)));

static __device__ __forceinline__ ushort f2bf(float x) {
    union { float f; unsigned u; } v; v.f = x;
    unsigned r = v.u + 0x7FFFu + ((v.u >> 16) & 1u);   // round-to-nearest-even
    return (ushort)(r >> 16);
}

// async global->LDS, 16B per lane; LDS dest = wave-uniform base + lane*16
static __device__ __forceinline__ void gload_lds16(const void* g, void* l) {
    __builtin_amdgcn_global_load_lds(
        (const __attribute__((address_space(1))) void*)g,
        (__attribute__((address_space(3))) void*)l, 16, 0, 0);
}

// ---------------- W2 + W1 f32 -> bf16 (canonical row-major) ----------------
__global__ void convert_w_kernel(const float* __restrict__ w2, ushort* __restrict__ w2b,
                                 const float* __restrict__ w1, ushort* __restrict__ w1b) {
    int i = blockIdx.x * 256 + threadIdx.x;
    const float* src; ushort* dst; int j;
    if (i < 131072) { src = w2; dst = w2b; j = i; }
    else            { src = w1; dst = w1b; j = i - 131072; if (j >= 12288) return; }
    float4 v = ((const float4*)src)[j];
    ushort4 o;
    o.x = f2bf(v.x); o.y = f2bf(v.y); o.z = f2bf(v.z); o.w = f2bf(v.w);
    ((ushort4*)dst)[j] = o;
}

// ---------------- layer 1: single-pass per segment (round-13 best, 584.9us total) ----------------
__global__ __launch_bounds__(512, 2) void layer1_kernel(
    const float* __restrict__ hstate, const float* __restrict__ ebpr,
    const float* __restrict__ Wsp, const ushort* __restrict__ W1b,
    const float* __restrict__ g1, const float* __restrict__ be1,
    ushort* __restrict__ h1)
{
    __shared__ __align__(16) ushort As[SEGROWS * 104];   // mlp_in [256][96] pad->104
    __shared__ __align__(16) ushort Bs[SEGROWS * 104];   // W1 half [256][96] pad->104
    __shared__ float statsS[8][4][16];
    __shared__ float statsQ[8][4][16];

    const int seg  = blockIdx.x;
    const int tid  = threadIdx.x;
    const int lane = tid & 63, wid = tid >> 6;
    const int wr   = wid >> 2, wc = wid & 3;

    // --- A cols 32..95 = h_state: one ds_write_b128 per 8 floats ---
    {
        const float4* hs4 = (const float4*)(hstate + (size_t)seg * SEGROWS * HD);
        #pragma unroll
        for (int i = 0; i < 4; ++i) {
            int u = tid + i * 512;                 // 2048 8-float chunks
            int r = u >> 3, c8 = u & 7;
            float4 v0 = hs4[2 * u];
            float4 v1 = hs4[2 * u + 1];
            s16x8 o;
            o[0] = (short)f2bf(v0.x); o[1] = (short)f2bf(v0.y);
            o[2] = (short)f2bf(v0.z); o[3] = (short)f2bf(v0.w);
            o[4] = (short)f2bf(v1.x); o[5] = (short)f2bf(v1.y);
            o[6] = (short)f2bf(v1.z); o[7] = (short)f2bf(v1.w);
            *(s16x8*)&As[r * 104 + DEMB + c8 * 8] = o;
        }
    }
    // --- A cols 0..31 = rel_emb: one ds_write_b64 per 4 outputs ---
    {
        #pragma unroll
        for (int i = 0; i < 4; ++i) {
            int u = tid + i * 512;                 // 2048 k-quads
            int r = u >> 3, kq = u & 7;
            float4 e = ((const float4*)ebpr)[seg * SEGROWS + r];
            s16x4 o;
            #pragma unroll
            for (int t = 0; t < 4; ++t) {
                float4 w = ((const float4*)Wsp)[kq * 4 + t];
                // pos = [e0, e2, e1, e3] (transpose (0,2,1) of (2,BF))
                float val = w.x * e.x + w.y * e.z + w.z * e.y + w.w * e.w;
                o[t] = (short)f2bf(val);           // b_sp cancels through segment BN
            }
            *(s16x4*)&As[r * 104 + kq * 4] = o;
        }
    }

    #pragma unroll 1
    for (int ct = 0; ct < 2; ++ct) {
        // --- B tile: pre-converted W1b rows ct*256..+256 ---
        {
            const s16x8* w18 = (const s16x8*)(W1b + (size_t)ct * 256 * DPRE);
            #pragma unroll
            for (int i = 0; i < 6; ++i) {
                int u = tid + i * 512;             // 3072 16B chunks
                int r = u / 12, c8 = u % 12;
                *(s16x8*)&Bs[r * 104 + c8 * 8] = w18[u];
            }
        }
        __syncthreads();                           // As and Bs ready

        f32x4 acc[8][4] = {};
        const int arow0 = wr * 128 + (lane & 15);
        const int bcol0 = wc * 64  + (lane & 15);
        const int kg    = (lane >> 4) * 8;
        #pragma unroll
        for (int ks = 0; ks < 3; ++ks) {
            s16x8 af[8], bfr[4];
            #pragma unroll
            for (int m = 0; m < 8; ++m)
                af[m] = *(const s16x8*)&As[(arow0 + m * 16) * 104 + ks * 32 + kg];
            #pragma unroll
            for (int n = 0; n < 4; ++n)
                bfr[n] = *(const s16x8*)&Bs[(bcol0 + n * 16) * 104 + ks * 32 + kg];
            #pragma unroll
            for (int m = 0; m < 8; ++m)
                #pragma unroll
                for (int n = 0; n < 4; ++n)
                    acc[m][n] = __builtin_amdgcn_mfma_f32_16x16x32_bf16(af[m], bfr[n], acc[m][n], 0, 0, 0);
        }

        // --- per-column stats over the 256 segment rows ---
        float s[4], q[4];
        #pragma unroll
        for (int n = 0; n < 4; ++n) { s[n] = 0.f; q[n] = 0.f; }
        #pragma unroll
        for (int m = 0; m < 8; ++m)
            #pragma unroll
            for (int n = 0; n < 4; ++n)
                #pragma unroll
                for (int j = 0; j < 4; ++j) { float v = acc[m][n][j]; s[n] += v; q[n] += v * v; }
        #pragma unroll
        for (int n = 0; n < 4; ++n) {
            s[n] += __shfl_xor(s[n], 16); q[n] += __shfl_xor(q[n], 16);
            s[n] += __shfl_xor(s[n], 32); q[n] += __shfl_xor(q[n], 32);
        }
        if ((lane >> 4) == 0) {
            #pragma unroll
            for (int n = 0; n < 4; ++n) { statsS[wid][n][lane] = s[n]; statsQ[wid][n][lane] = q[n]; }
        }
        __syncthreads();

        const float inv256 = 1.0f / 256.0f;
        float aa[4], bb[4];
        const int c16 = lane & 15;
        #pragma unroll
        for (int n = 0; n < 4; ++n) {
            float sum = statsS[wc][n][c16] + statsS[4 + wc][n][c16];
            float sq  = statsQ[wc][n][c16] + statsQ[4 + wc][n][c16];
            float mean = sum * inv256;
            float var  = sq * inv256 - mean * mean;
            float rinv = rsqrtf(var + EPSB);
            int col = ct * 256 + wc * 64 + n * 16 + c16;
            aa[n] = g1[col] * rinv;
            bb[n] = be1[col] - mean * aa[n];
        }

        ushort* outp = h1 + (size_t)(seg * SEGROWS) * N1 + ct * 256;
        const int rbase = wr * 128 + (lane >> 4) * 4;
        #pragma unroll
        for (int m = 0; m < 8; ++m)
            #pragma unroll
            for (int j = 0; j < 4; ++j) {
                int r = rbase + m * 16 + j;
                ushort* rowp = outp + (size_t)r * N1 + wc * 64 + c16;
                #pragma unroll
                for (int n = 0; n < 4; ++n) {
                    float v = acc[m][n][j] * aa[n] + bb[n];
                    v = v > 0.f ? v : 0.f;
                    rowp[n * 16] = f2bf(v);
                }
            }
        __syncthreads();   // Bs/stats dead before next ct
    }
}

// ==================== layer 2: 8-phase 256x256 template (round-3 structure; final) ====================
// Ledger R1-R15: schedule depth, narrow-tile occupancy (x4 attempts), launch-
// bound occupancy, fusion, epilogue restructure, and MFMA shape all regressed
// or were neutral against this structure. It is latency-bound at 1 block/CU
// (NOT at a hardware roofline), but every structural escape loses more to
// A-panel refetch or register spill than it recovers. Locked in as final.

static __device__ __forceinline__ void stage_half(
    const char* gsrc, char* ldst, int kt, int wid, int lane)
{
    const int row = (wid << 3) + (lane >> 3);      // 0..63 within an 8KB round
    const int cl  = (lane & 7) ^ (lane >> 3);      // inverse-swizzled source chunk
    const char* g = gsrc + (size_t)row * 1024 + (size_t)kt * 128 + cl * 16;
    gload_lds16(g,          ldst + wid * 1024);
    gload_lds16(g + 65536,  ldst + 8192 + wid * 1024);   // +64 rows
}

static __device__ __forceinline__ void read_a4(
    s16x8 (&dst)[4][2], const ushort* base, int arow0, int mofs, int ko0, int ko1)
{
    #pragma unroll
    for (int mi = 0; mi < 4; ++mi) {
        const ushort* p = base + (arow0 + (mofs + mi) * 16) * 64;
        dst[mi][0] = *(const s16x8*)(p + ko0);
        dst[mi][1] = *(const s16x8*)(p + ko1);
    }
}
static __device__ __forceinline__ void read_b2(
    s16x8 (&dst)[2][2], const ushort* base, int bcol0, int nofs, int ko0, int ko1)
{
    #pragma unroll
    for (int ni = 0; ni < 2; ++ni) {
        const ushort* p = base + (bcol0 + (nofs + ni) * 16) * 64;
        dst[ni][0] = *(const s16x8*)(p + ko0);
        dst[ni][1] = *(const s16x8*)(p + ko1);
    }
}
static __device__ __forceinline__ void mfma_q(
    f32x4 (&acc)[8][4], const s16x8 (&af)[4][2], const s16x8 (&bfr)[2][2],
    int mofs, int nofs)
{
    __builtin_amdgcn_s_setprio(1);
    #pragma unroll
    for (int mi = 0; mi < 4; ++mi)
        #pragma unroll
        for (int ni = 0; ni < 2; ++ni) {
            f32x4 c = acc[mofs + mi][nofs + ni];
            c = __builtin_amdgcn_mfma_f32_16x16x32_bf16(af[mi][0], bfr[ni][0], c, 0, 0, 0);
            c = __builtin_amdgcn_mfma_f32_16x16x32_bf16(af[mi][1], bfr[ni][1], c, 0, 0, 0);
            acc[mofs + mi][nofs + ni] = c;
        }
    __builtin_amdgcn_s_setprio(0);
}

#define PHASE_BAR() do { __builtin_amdgcn_sched_barrier(0); \
    asm volatile("s_barrier" ::: "memory"); \
    __builtin_amdgcn_sched_barrier(0); } while (0)

__global__ __launch_bounds__(512, 2) void layer2_kernel(
    const ushort* __restrict__ h1, const ushort* __restrict__ W2b,
    const float* __restrict__ g2, const float* __restrict__ be2,
    float* __restrict__ out)
{
    __shared__ __align__(16) ushort Asl[2 * 256 * 64];   // 2 x 32 KiB (A0,A1 halves)
    __shared__ __align__(16) ushort Bsl[2 * 256 * 64];   // 2 x 32 KiB (B0,B1 halves)
    __shared__ float statsS[8][4][16];
    __shared__ float statsQ[8][4][16];

    const int b   = blockIdx.x;
    const int wg  = (b & 7) * 512 + (b >> 3);
    const int seg = wg >> 2;
    const int ct  = wg & 3;

    const int tid  = threadIdx.x;
    const int lane = tid & 63, wid = tid >> 6;
    const int wr   = wid >> 2, wc = wid & 3;

    const char* srcA = (const char*)(h1  + (size_t)seg * SEGROWS * N1);
    const char* srcB = (const char*)(W2b + (size_t)ct  * 256    * N1);

    f32x4 acc[8][4] = {};
    const int arow0 = wr * 128 + (lane & 15);
    const int bcol0 = wc * 64  + (lane & 15);
    const int ko0 = (((lane >> 4)    ) ^ (lane & 7)) * 8;
    const int ko1 = (((lane >> 4) + 4) ^ (lane & 7)) * 8;

    // prologue: A0(0) A1(0) B0(0) B1(0) A0(1)  (10 loads/thread)
    stage_half(srcA,          (char*)Asl,          0, wid, lane);
    stage_half(srcA + 131072, (char*)Asl + 16384,  0, wid, lane);
    stage_half(srcB,          (char*)Bsl,          0, wid, lane);
    stage_half(srcB + 131072, (char*)Bsl + 16384,  0, wid, lane);
    stage_half(srcA,          (char*)Asl + 32768,  1, wid, lane);
    asm volatile("s_waitcnt vmcnt(2)" ::: "memory");   // tile 0 landed; A0(1) in flight
    PHASE_BAR();

#define L2_TILE(U, VW)                                                              \
    {                                                                               \
        const ushort* Ab = Asl + ((U) & 1) * 16384;                                 \
        const ushort* Bb = Bsl + ((U) & 1) * 16384;                                 \
        char* Acur = (char*)Asl + ((U) & 1) * 32768;                                \
        char* An   = (char*)Asl + (((U) + 1) & 1) * 32768;                          \
        char* Bn   = (char*)Bsl + (((U) + 1) & 1) * 32768;                          \
        s16x8 a03[4][2], a47[4][2], b01[2][2], b23[2][2];                           \
        read_a4(a03, Ab, arow0, 0, ko0, ko1);                                       \
        read_b2(b01, Bb, bcol0, 0, ko0, ko1);                                       \
        if ((U) + 1 < 8) stage_half(srcA + 131072, An + 16384, (U) + 1, wid, lane); \
        PHASE_BAR();                                                                \
        mfma_q(acc, a03, b01, 0, 0);                                                \
        read_a4(a47, Ab, arow0, 4, ko0, ko1);                                       \
        if ((U) + 1 < 8) stage_half(srcB, Bn, (U) + 1, wid, lane);                  \
        PHASE_BAR();                                                                \
        mfma_q(acc, a47, b01, 4, 0);                                                \
        read_b2(b23, Bb, bcol0, 2, ko0, ko1);                                       \
        if ((U) + 1 < 8) stage_half(srcB + 131072, Bn + 16384, (U) + 1, wid, lane); \
        PHASE_BAR();                                                                \
        mfma_q(acc, a47, b23, 4, 2);                                                \
        if ((U) + 2 < 8) stage_half(srcA, Acur, (U) + 2, wid, lane);                \
        asm volatile("s_waitcnt vmcnt(" #VW ")" ::: "memory");                      \
        PHASE_BAR();                                                                \
        mfma_q(acc, a03, b23, 0, 2);                                                \
    }

    L2_TILE(0, 2) L2_TILE(1, 2) L2_TILE(2, 2) L2_TILE(3, 2)
    L2_TILE(4, 2) L2_TILE(5, 2) L2_TILE(6, 0) L2_TILE(7, 0)
#undef L2_TILE

    // --- per-column stats over the 256 segment rows ---
    float s[4], q[4];
    #pragma unroll
    for (int n = 0; n < 4; ++n) { s[n] = 0.f; q[n] = 0.f; }
    #pragma unroll
    for (int m = 0; m < 8; ++m)
        #pragma unroll
        for (int n = 0; n < 4; ++n)
            #pragma unroll
            for (int j = 0; j < 4; ++j) { float v = acc[m][n][j]; s[n] += v; q[n] += v * v; }
    #pragma unroll
    for (int n = 0; n < 4; ++n) {
        s[n] += __shfl_xor(s[n], 16); q[n] += __shfl_xor(q[n], 16);
        s[n] += __shfl_xor(s[n], 32); q[n] += __shfl_xor(q[n], 32);
    }
    if ((lane >> 4) == 0) {
        #pragma unroll
        for (int n = 0; n < 4; ++n) { statsS[wid][n][lane] = s[n]; statsQ[wid][n][lane] = q[n]; }
    }
    __syncthreads();

    const float inv256 = 1.0f / 256.0f;
    float aa[4], bb[4];
    const int c16 = lane & 15;
    #pragma unroll
    for (int n = 0; n < 4; ++n) {
        float sum = statsS[wc][n][c16] + statsS[4 + wc][n][c16];
        float sq  = statsQ[wc][n][c16] + statsQ[4 + wc][n][c16];
        float mean = sum * inv256;
        float var  = sq * inv256 - mean * mean;
        float rinv = rsqrtf(var + EPSB);
        int col = ct * 256 + wc * 64 + n * 16 + c16;
        aa[n] = g2[col] * rinv;
        bb[n] = be2[col] - mean * aa[n];
    }

    float* outp = out + (size_t)(seg * SEGROWS) * N2 + ct * 256;
    const int rbase = wr * 128 + (lane >> 4) * 4;
    #pragma unroll
    for (int m = 0; m < 8; ++m)
        #pragma unroll
        for (int j = 0; j < 4; ++j) {
            int r = rbase + m * 16 + j;
            float* rowp = outp + (size_t)r * N2 + wc * 64 + c16;
            #pragma unroll
            for (int n = 0; n < 4; ++n) {
                float v = acc[m][n][j] * aa[n] + bb[n];
                v = v > 0.f ? v : 0.f;
                rowp[n * 16] = v;
            }
        }
}

extern "C" void kernel_launch(void* const* d_in, const int* in_sizes, int n_in,
                              void* d_out, int out_size, void* d_ws, size_t ws_size,
                              hipStream_t stream) {
    const float* hstate = (const float*)d_in[0];
    const float* ebpr   = (const float*)d_in[1];
    const float* Wsp    = (const float*)d_in[2];
    // d_in[3] = b_sp  : cancels through segment BN (exact)
    const float* W1     = (const float*)d_in[4];
    // d_in[5] = b1    : cancels through segment BN (exact)
    const float* g1     = (const float*)d_in[6];
    const float* be1    = (const float*)d_in[7];
    const float* W2     = (const float*)d_in[8];
    // d_in[9] = b2    : cancels through segment BN (exact)
    const float* g2     = (const float*)d_in[10];
    const float* be2    = (const float*)d_in[11];
    float* outp         = (float*)d_out;

    ushort* h1  = (ushort*)d_ws;                          // 262144 x 512 bf16 = 256 MiB
    ushort* W2b = h1 + (size_t)TOTALROWS * N1;            // 1024 x 512 bf16 = 1 MiB
    ushort* W1b = W2b + (size_t)N2 * N1;                  // 512 x 96 bf16

    convert_w_kernel<<<dim3(560), dim3(256), 0, stream>>>(W2, W2b, W1, W1b);
    layer1_kernel<<<dim3(NSEG), dim3(512), 0, stream>>>(hstate, ebpr, Wsp, W1b, g1, be1, h1);
    layer2_kernel<<<dim3(4096), dim3(512), 0, stream>>>(h1, W2b, g2, be2, outp);
}